// Round 1
// baseline (2456.611 us; speedup 1.0000x reference)
//
#include <hip/hip_runtime.h>
#include <hip/hip_bf16.h>

typedef unsigned short u16;
typedef __bf16 bf16x8 __attribute__((ext_vector_type(8)));
typedef float f32x4 __attribute__((ext_vector_type(4)));

#define RESOLUTION 7
#define SR 2
#define SS 14
#define NSAMP 196

// ---------------------------------------------------------------------------
// f32 -> bf16 convert (grid-stride)
// ---------------------------------------------------------------------------
__global__ void f32_to_bf16_kernel(const float* __restrict__ in,
                                   __hip_bfloat16* __restrict__ out, int n) {
    int idx = blockIdx.x * blockDim.x + threadIdx.x;
    int stride = gridDim.x * blockDim.x;
    for (int i = idx; i < n; i += stride)
        out[i] = __float2bfloat16(in[i]);
}

// ---------------------------------------------------------------------------
// concat head weights (1024 x 100) + bias (100)
// cols: [0,4)=cate, [4,22)=bbox3d, [22,58)=yawc, [58,94)=yawr, [94,100)=hgt
// ---------------------------------------------------------------------------
__global__ void head_concat_kernel(
    const float* __restrict__ cate_w, const float* __restrict__ bbox3d_w,
    const float* __restrict__ yawc_w, const float* __restrict__ yawr_w,
    const float* __restrict__ hgt_w,
    const float* __restrict__ cate_b, const float* __restrict__ bbox3d_b,
    const float* __restrict__ yawc_b, const float* __restrict__ yawr_b,
    const float* __restrict__ hgt_b,
    float* __restrict__ wh, float* __restrict__ bh) {
    int idx = blockIdx.x * blockDim.x + threadIdx.x;
    if (idx < 1024 * 100) {
        int k = idx / 100, c = idx % 100;
        float v;
        if (c < 4)        v = cate_w[k * 4 + c];
        else if (c < 22)  v = bbox3d_w[k * 18 + (c - 4)];
        else if (c < 58)  v = yawc_w[k * 36 + (c - 22)];
        else if (c < 94)  v = yawr_w[k * 36 + (c - 58)];
        else              v = hgt_w[k * 6 + (c - 94)];
        wh[idx] = v;
    }
    if (idx < 100) {
        int c = idx;
        float v;
        if (c < 4)        v = cate_b[c];
        else if (c < 22)  v = bbox3d_b[c - 4];
        else if (c < 58)  v = yawc_b[c - 22];
        else if (c < 94)  v = yawr_b[c - 58];
        else              v = hgt_b[c - 94];
        bh[c] = v;
    }
}

// ---------------------------------------------------------------------------
// ROI align: one block per (b,n) box; 256 threads = 256 channels.
// Writes x row (12544 bf16) coalesced via LDS transpose.
// col layout = c*49 + ph*7 + pw  (matches pooled.reshape(C,7,7).flatten)
// ---------------------------------------------------------------------------
__global__ __launch_bounds__(256) void roi_align_kernel(
    const float* __restrict__ feat0, const float* __restrict__ feat1,
    const float* __restrict__ feat2, const float* __restrict__ bbox2d,
    const int* __restrict__ anchor_id, __hip_bfloat16* __restrict__ xb,
    int B, int N, int C) {
    int bn = blockIdx.x;
    int b = bn / N;
    int tid = threadIdx.x;

    __shared__ int s_y0[NSAMP], s_x0[NSAMP], s_y1[NSAMP], s_x1[NSAMP];
    __shared__ float s_ly[NSAMP], s_lx[NSAMP], s_valid[NSAMP];
    __shared__ __hip_bfloat16 s_pool[256 * 49];

    float cy = bbox2d[bn * 4 + 0], cx = bbox2d[bn * 4 + 1];
    float hh = bbox2d[bn * 4 + 2], ww = bbox2d[bn * 4 + 3];
    int lvl = anchor_id[bn] / 3;
    float scale = (lvl == 0) ? 0.25f : ((lvl == 1) ? 0.125f : 0.0625f);
    int H = (lvl == 0) ? 128 : ((lvl == 1) ? 64 : 32);
    int W = H;
    const float* feat = (lvl == 0) ? feat0 : ((lvl == 1) ? feat1 : feat2);

    float t = cy - hh * 0.5f, l = cx - ww * 0.5f;
    float btm = cy + hh * 0.5f, r = cx + ww * 0.5f;
    float sy = t * scale - 0.5f, sx = l * scale - 0.5f;
    float bh = (btm - t) * scale * (1.0f / RESOLUTION);
    float bw = (r - l) * scale * (1.0f / RESOLUTION);

    if (tid < NSAMP) {
        int i = tid / SS, j = tid % SS;
        float gi = (i + 0.5f) * (1.0f / SR);
        float gj = (j + 0.5f) * (1.0f / SR);
        float y = sy + gi * bh, x = sx + gj * bw;
        float valid = (y > -1.0f && y < (float)H && x > -1.0f && x < (float)W)
                          ? 1.0f : 0.0f;
        y = fminf(fmaxf(y, 0.0f), (float)(H - 1));
        x = fminf(fmaxf(x, 0.0f), (float)(W - 1));
        int y0 = (int)floorf(y), x0 = (int)floorf(x);
        int y1 = min(y0 + 1, H - 1), x1 = min(x0 + 1, W - 1);
        s_y0[tid] = y0; s_x0[tid] = x0; s_y1[tid] = y1; s_x1[tid] = x1;
        s_ly[tid] = y - (float)y0; s_lx[tid] = x - (float)x0;
        s_valid[tid] = valid;
    }
    __syncthreads();

    int c = tid;
    const float* fp = feat + ((size_t)(b * C + c)) * H * W;
    for (int ph = 0; ph < RESOLUTION; ++ph) {
        for (int pw = 0; pw < RESOLUTION; ++pw) {
            float acc = 0.f;
            #pragma unroll
            for (int dy = 0; dy < SR; ++dy) {
                #pragma unroll
                for (int dx = 0; dx < SR; ++dx) {
                    int si = (ph * SR + dy) * SS + (pw * SR + dx);
                    int y0 = s_y0[si], x0 = s_x0[si];
                    int y1 = s_y1[si], x1 = s_x1[si];
                    float ly = s_ly[si], lx = s_lx[si];
                    float hy = 1.f - ly, hx = 1.f - lx;
                    float v = fp[y0 * W + x0] * (hy * hx)
                            + fp[y0 * W + x1] * (hy * lx)
                            + fp[y1 * W + x0] * (ly * hx)
                            + fp[y1 * W + x1] * (ly * lx);
                    acc += v * s_valid[si];
                }
            }
            s_pool[c * 49 + ph * 7 + pw] = __float2bfloat16(acc * 0.25f);
        }
    }
    __syncthreads();

    __hip_bfloat16* xr = xb + (size_t)bn * 12544;
    #pragma unroll
    for (int i = 0; i < 49; ++i)
        xr[i * 256 + tid] = s_pool[i * 256 + tid];
}

// ---------------------------------------------------------------------------
// bf16 MFMA GEMM: C(M,N) = A(M,K) @ B(K,N) + bias
// 64x64 tile, BK=32, 256 threads = 4 waves; wave w: rows [16w,16w+16), 4 n-tiles
// mfma_f32_16x16x32_bf16: A[m=lane&15][k=(lane>>4)*8+j],
//                         B[k=(lane>>4)*8+j][n=lane&15],
//                         D: col=lane&15, row=(lane>>4)*4+reg   (m89-verified)
// ---------------------------------------------------------------------------
#define LDSTR 40  // padded LDS row stride in u16 (80 B -> 2-way bank alias, free)

__global__ __launch_bounds__(256) void gemm_bias_kernel(
    const u16* __restrict__ A, const u16* __restrict__ Bw,
    const float* __restrict__ bias, float* __restrict__ Cout,
    int M, int N, int K) {
    __shared__ u16 lds_a[64 * LDSTR];
    __shared__ u16 lds_b[64 * LDSTR];
    int m0 = blockIdx.x * 64;
    int n0 = blockIdx.y * 64;
    int tid = threadIdx.x;
    int wave = tid >> 6, lane = tid & 63;

    f32x4 acc[4] = {};

    int ar = tid >> 2, ak = (tid & 3) * 8;   // A staging: 64 rows x 32 k
    int bk = tid >> 3, bn8 = (tid & 7) * 8;  // B staging: 32 k x 64 n

    for (int k0 = 0; k0 < K; k0 += 32) {
        uint4 av = *(const uint4*)(A + (size_t)(m0 + ar) * K + k0 + ak);
        uint4 bv = *(const uint4*)(Bw + (size_t)(k0 + bk) * N + n0 + bn8);
        *(uint4*)&lds_a[ar * LDSTR + ak] = av;
        union { uint4 v; u16 s[8]; } bu; bu.v = bv;
        #pragma unroll
        for (int j = 0; j < 8; ++j)
            lds_b[(bn8 + j) * LDSTR + bk] = bu.s[j];
        __syncthreads();

        bf16x8 af = *(const bf16x8*)&lds_a[(wave * 16 + (lane & 15)) * LDSTR + (lane >> 4) * 8];
        #pragma unroll
        for (int tn = 0; tn < 4; ++tn) {
            bf16x8 bf = *(const bf16x8*)&lds_b[(tn * 16 + (lane & 15)) * LDSTR + (lane >> 4) * 8];
            acc[tn] = __builtin_amdgcn_mfma_f32_16x16x32_bf16(af, bf, acc[tn], 0, 0, 0);
        }
        __syncthreads();
    }

    int col = lane & 15, rquad = lane >> 4;
    #pragma unroll
    for (int tn = 0; tn < 4; ++tn) {
        int nn = n0 + tn * 16 + col;
        float bs = bias[nn];
        #pragma unroll
        for (int rg = 0; rg < 4; ++rg) {
            int mm = m0 + wave * 16 + rquad * 4 + rg;
            Cout[(size_t)mm * N + nn] = acc[tn][rg] + bs;
        }
    }
}

// ---------------------------------------------------------------------------
// BN stats: per-column mean & rstd over M rows. grid = N/64, block 256 = 64x4
// ---------------------------------------------------------------------------
__global__ __launch_bounds__(256) void bn_stats_kernel(
    const float* __restrict__ y, float* __restrict__ stats, int M, int N) {
    int cx = threadIdx.x & 63, rg = threadIdx.x >> 6;
    int col = blockIdx.x * 64 + cx;
    float s = 0.f, sq = 0.f;
    for (int r = rg; r < M; r += 4) {
        float v = y[(size_t)r * N + col];
        s += v; sq += v * v;
    }
    __shared__ float ls[4][64], lq[4][64];
    ls[rg][cx] = s; lq[rg][cx] = sq;
    __syncthreads();
    if (rg == 0) {
        s = ls[0][cx] + ls[1][cx] + ls[2][cx] + ls[3][cx];
        sq = lq[0][cx] + lq[1][cx] + lq[2][cx] + lq[3][cx];
        float mean = s / (float)M;
        float var = sq / (float)M - mean * mean;
        stats[col] = mean;
        stats[N + col] = rsqrtf(var + 1e-5f);
    }
}

// ---------------------------------------------------------------------------
// BN apply + relu -> bf16.  N hardcoded 1024.
// ---------------------------------------------------------------------------
__global__ void bn_apply_kernel(const float* __restrict__ y,
                                const float* __restrict__ stats,
                                const float* __restrict__ g,
                                const float* __restrict__ b,
                                __hip_bfloat16* __restrict__ xo, int total) {
    int idx = blockIdx.x * blockDim.x + threadIdx.x;
    if (idx >= total) return;
    int col = idx & 1023;
    float v = (y[idx] - stats[col]) * stats[1024 + col] * g[col] + b[col];
    xo[idx] = __float2bfloat16(fmaxf(v, 0.f));
}

// ---------------------------------------------------------------------------
// heads: out(2048,100) = x(2048,1024)bf16 @ wh(1024,100)f32 + bh
// one block per row; x row staged to LDS as f32
// ---------------------------------------------------------------------------
__global__ __launch_bounds__(128) void heads_kernel(
    const __hip_bfloat16* __restrict__ x, const float* __restrict__ wh,
    const float* __restrict__ bh, float* __restrict__ out) {
    int m = blockIdx.x;
    __shared__ float lx[1024];
    for (int k = threadIdx.x; k < 1024; k += 128)
        lx[k] = __bfloat162float(x[(size_t)m * 1024 + k]);
    __syncthreads();
    int n = threadIdx.x;
    if (n < 100) {
        float acc = bh[n];
        for (int k = 0; k < 1024; ++k)
            acc += lx[k] * wh[k * 100 + n];
        out[(size_t)m * 100 + n] = acc;
    }
}

// ---------------------------------------------------------------------------
extern "C" void kernel_launch(void* const* d_in, const int* in_sizes, int n_in,
                              void* d_out, int out_size, void* d_ws, size_t ws_size,
                              hipStream_t stream) {
    const float* feat0   = (const float*)d_in[0];
    const float* feat1   = (const float*)d_in[1];
    const float* feat2   = (const float*)d_in[2];
    const float* bbox2d  = (const float*)d_in[3];
    const int*   anchor  = (const int*)d_in[4];
    const float* fc1_w   = (const float*)d_in[5];
    const float* fc1_b   = (const float*)d_in[6];
    const float* bn1_g   = (const float*)d_in[7];
    const float* bn1_b   = (const float*)d_in[8];
    const float* fc2_w   = (const float*)d_in[9];
    const float* fc2_b   = (const float*)d_in[10];
    const float* bn2_g   = (const float*)d_in[11];
    const float* bn2_b   = (const float*)d_in[12];
    const float* cate_w  = (const float*)d_in[13];
    const float* cate_b  = (const float*)d_in[14];
    const float* bbox3d_w= (const float*)d_in[15];
    const float* bbox3d_b= (const float*)d_in[16];
    const float* yawc_w  = (const float*)d_in[17];
    const float* yawc_b  = (const float*)d_in[18];
    const float* yawr_w  = (const float*)d_in[19];
    const float* yawr_b  = (const float*)d_in[20];
    const float* hgt_w   = (const float*)d_in[21];
    const float* hgt_b   = (const float*)d_in[22];

    const int B = 4, N = 512, C = 256, FC = 1024;
    const int M = B * N;            // 2048
    const int K1 = C * 49;          // 12544

    char* p = (char*)d_ws;
    auto carve = [&](size_t bytes) {
        char* r = p;
        p += (bytes + 255) & ~(size_t)255;
        return r;
    };
    u16*   xb    = (u16*)carve((size_t)M * K1 * 2);
    u16*   w1b   = (u16*)carve((size_t)K1 * FC * 2);
    u16*   w2b   = (u16*)carve((size_t)FC * FC * 2);
    float* y     = (float*)carve((size_t)M * FC * 4);
    u16*   x1b   = (u16*)carve((size_t)M * FC * 2);
    float* stats = (float*)carve(2 * FC * 4);
    float* wh    = (float*)carve((size_t)FC * 100 * 4);
    float* bhd   = (float*)carve(100 * 4);
    float* outp  = (float*)d_out;

    // 1. weight conversions
    {
        int n1 = K1 * FC;
        f32_to_bf16_kernel<<<(n1 + 255) / 256, 256, 0, stream>>>(
            fc1_w, (__hip_bfloat16*)w1b, n1);
        int n2 = FC * FC;
        f32_to_bf16_kernel<<<(n2 + 255) / 256, 256, 0, stream>>>(
            fc2_w, (__hip_bfloat16*)w2b, n2);
    }
    // 2. head weight concat
    head_concat_kernel<<<(1024 * 100 + 255) / 256, 256, 0, stream>>>(
        cate_w, bbox3d_w, yawc_w, yawr_w, hgt_w,
        cate_b, bbox3d_b, yawc_b, yawr_b, hgt_b, wh, bhd);
    // 3. ROI align -> x bf16 (M, K1)
    roi_align_kernel<<<M, 256, 0, stream>>>(
        feat0, feat1, feat2, bbox2d, anchor, (__hip_bfloat16*)xb, B, N, C);
    // 4. fc1 GEMM
    gemm_bias_kernel<<<dim3(M / 64, FC / 64), 256, 0, stream>>>(
        xb, w1b, fc1_b, y, M, FC, K1);
    // 5. BN1
    bn_stats_kernel<<<FC / 64, 256, 0, stream>>>(y, stats, M, FC);
    bn_apply_kernel<<<(M * FC + 255) / 256, 256, 0, stream>>>(
        y, stats, bn1_g, bn1_b, (__hip_bfloat16*)x1b, M * FC);
    // 6. fc2 GEMM
    gemm_bias_kernel<<<dim3(M / 64, FC / 64), 256, 0, stream>>>(
        x1b, w2b, fc2_b, y, M, FC, FC);
    // 7. BN2 (reuse x1b as x2 bf16)
    bn_stats_kernel<<<FC / 64, 256, 0, stream>>>(y, stats, M, FC);
    bn_apply_kernel<<<(M * FC + 255) / 256, 256, 0, stream>>>(
        y, stats, bn2_g, bn2_b, (__hip_bfloat16*)x1b, M * FC);
    // 8. heads -> d_out
    heads_kernel<<<M, 128, 0, stream>>>((const __hip_bfloat16*)x1b, wh, bhd, outp);
}

// Round 2
// 827.233 us; speedup vs baseline: 2.9697x; 2.9697x over previous
//
#include <hip/hip_runtime.h>
#include <hip/hip_bf16.h>

typedef unsigned short u16;
typedef unsigned int u32;
typedef __bf16 bf16x8 __attribute__((ext_vector_type(8)));
typedef float f32x4 __attribute__((ext_vector_type(4)));

#define RESOLUTION 7
#define SR 2
#define SS 14
#define NSAMP 196

static __device__ __forceinline__ u16 f2bf(float f) {
    __hip_bfloat16 t = __float2bfloat16(f);
    return *reinterpret_cast<u16*>(&t);
}
static __device__ __forceinline__ float bf2f(u16 h) {
    return __uint_as_float(((u32)h) << 16);
}

// ---------------------------------------------------------------------------
// feat (B,C,H,W) f32  ->  (B,HW,C) bf16.  C=256.
// block: 64 hw positions x 256 channels, tiled through LDS [c][hw+pad].
// ---------------------------------------------------------------------------
__global__ __launch_bounds__(256) void transpose_feat_kernel(
    const float* __restrict__ in, u16* __restrict__ out, int HW) {
    int b = blockIdx.y;
    int hw0 = blockIdx.x * 64;
    __shared__ u16 tile[256][65];  // [c][hw], pad 65 -> odd stride, conflict-free

    int hwo = threadIdx.x & 63;
    int c0 = threadIdx.x >> 6;  // 0..3
    for (int cc = 0; cc < 256; cc += 4) {
        int c = cc + c0;
        float v = in[((size_t)(b * 256 + c)) * HW + hw0 + hwo];
        tile[c][hwo] = f2bf(v);
    }
    __syncthreads();

    // write: 32-lane group covers 256 channels (8 ch/thread, 16B stores)
    int ro = threadIdx.x >> 5;        // 0..7
    int co = (threadIdx.x & 31) * 8;  // channel base
    for (int i = 0; i < 64; i += 8) {
        int hw = i + ro;
        union { uint4 v; u16 h[8]; } o;
        #pragma unroll
        for (int j = 0; j < 8; ++j) o.h[j] = tile[co + j][hw];
        *(uint4*)&out[((size_t)b * HW + hw0 + hw) * 256 + co] = o.v;
    }
}

// ---------------------------------------------------------------------------
// weight transpose: out (N=1024 rows, K cols) bf16 = in (K rows, 1024 cols) f32,
// with optional k-permutation  k = (kp&255)*49 + (kp>>8)  (fc1: kp = bin*256+c)
// ---------------------------------------------------------------------------
__global__ __launch_bounds__(256) void transpose_w_kernel(
    const float* __restrict__ in, u16* __restrict__ out, int K, int perm) {
    int kp0 = blockIdx.x * 64, n0 = blockIdx.y * 64;
    __shared__ u16 tile[64][65];  // [kp][n]

    int nn = threadIdx.x & 63, ks = threadIdx.x >> 6;
    for (int i = 0; i < 64; i += 4) {
        int kp = kp0 + ks + i;
        int k = perm ? ((kp & 255) * 49 + (kp >> 8)) : kp;
        tile[ks + i][nn] = f2bf(in[(size_t)k * 1024 + n0 + nn]);
    }
    __syncthreads();

    int nw = threadIdx.x >> 3, ko = (threadIdx.x & 7) * 8;
    for (int i = 0; i < 2; ++i) {
        int n = nw + i * 32;
        union { uint4 v; u16 h[8]; } o;
        #pragma unroll
        for (int j = 0; j < 8; ++j) o.h[j] = tile[ko + j][n];
        *(uint4*)&out[(size_t)(n0 + n) * K + kp0 + ko] = o.v;
    }
}

// ---------------------------------------------------------------------------
// concat head weights (1024 x 100) + bias (100)
// ---------------------------------------------------------------------------
__global__ void head_concat_kernel(
    const float* __restrict__ cate_w, const float* __restrict__ bbox3d_w,
    const float* __restrict__ yawc_w, const float* __restrict__ yawr_w,
    const float* __restrict__ hgt_w,
    const float* __restrict__ cate_b, const float* __restrict__ bbox3d_b,
    const float* __restrict__ yawc_b, const float* __restrict__ yawr_b,
    const float* __restrict__ hgt_b,
    float* __restrict__ wh, float* __restrict__ bh) {
    int idx = blockIdx.x * blockDim.x + threadIdx.x;
    if (idx < 1024 * 100) {
        int k = idx / 100, c = idx % 100;
        float v;
        if (c < 4)        v = cate_w[k * 4 + c];
        else if (c < 22)  v = bbox3d_w[k * 18 + (c - 4)];
        else if (c < 58)  v = yawc_w[k * 36 + (c - 22)];
        else if (c < 94)  v = yawr_w[k * 36 + (c - 58)];
        else              v = hgt_w[k * 6 + (c - 94)];
        wh[idx] = v;
    }
    if (idx < 100) {
        int c = idx;
        float v;
        if (c < 4)        v = cate_b[c];
        else if (c < 22)  v = bbox3d_b[c - 4];
        else if (c < 58)  v = yawc_b[c - 22];
        else if (c < 94)  v = yawr_b[c - 58];
        else              v = hgt_b[c - 94];
        bh[c] = v;
    }
}

// ---------------------------------------------------------------------------
// ROI align v2 on (B,HW,C) bf16 feats.
// Block = 1 box, 256 threads = 8 groups of 32 lanes.
// group g handles bins {g, g+8, ...}; lane handles 8 channels -> 16B tap loads.
// x row layout: k' = bin*256 + c  (fc1_w rows permuted to match).
// ---------------------------------------------------------------------------
__global__ __launch_bounds__(256) void roi_align_v2_kernel(
    const u16* __restrict__ tf0, const u16* __restrict__ tf1,
    const u16* __restrict__ tf2, const float* __restrict__ bbox2d,
    const int* __restrict__ anchor_id, u16* __restrict__ xb) {
    int bn = blockIdx.x;
    int b = bn >> 9;  // N=512
    int tid = threadIdx.x;

    __shared__ int s_o00[NSAMP], s_o01[NSAMP], s_o10[NSAMP], s_o11[NSAMP];
    __shared__ float s_w00[NSAMP], s_w01[NSAMP], s_w10[NSAMP], s_w11[NSAMP];

    float cy = bbox2d[bn * 4 + 0], cx = bbox2d[bn * 4 + 1];
    float hh = bbox2d[bn * 4 + 2], ww = bbox2d[bn * 4 + 3];
    int lvl = anchor_id[bn] / 3;
    float scale = (lvl == 0) ? 0.25f : ((lvl == 1) ? 0.125f : 0.0625f);
    int H = (lvl == 0) ? 128 : ((lvl == 1) ? 64 : 32);
    int W = H;

    float t = cy - hh * 0.5f, l = cx - ww * 0.5f;
    float btm = cy + hh * 0.5f, r = cx + ww * 0.5f;
    float sy = t * scale - 0.5f, sx = l * scale - 0.5f;
    float bh = (btm - t) * scale * (1.0f / RESOLUTION);
    float bw = (r - l) * scale * (1.0f / RESOLUTION);

    if (tid < NSAMP) {
        int i = tid / SS, j = tid % SS;
        float gi = (i + 0.5f) * (1.0f / SR);
        float gj = (j + 0.5f) * (1.0f / SR);
        float y = sy + gi * bh, x = sx + gj * bw;
        float valid = (y > -1.0f && y < (float)H && x > -1.0f && x < (float)W)
                          ? 0.25f : 0.0f;  // fold the 1/4 sample average in
        y = fminf(fmaxf(y, 0.0f), (float)(H - 1));
        x = fminf(fmaxf(x, 0.0f), (float)(W - 1));
        int y0 = (int)floorf(y), x0 = (int)floorf(x);
        int y1 = min(y0 + 1, H - 1), x1 = min(x0 + 1, W - 1);
        float ly = y - (float)y0, lx = x - (float)x0;
        float hy = 1.f - ly, hx = 1.f - lx;
        s_o00[tid] = (y0 * W + x0) * 256;
        s_o01[tid] = (y0 * W + x1) * 256;
        s_o10[tid] = (y1 * W + x0) * 256;
        s_o11[tid] = (y1 * W + x1) * 256;
        s_w00[tid] = hy * hx * valid;
        s_w01[tid] = hy * lx * valid;
        s_w10[tid] = ly * hx * valid;
        s_w11[tid] = ly * lx * valid;
    }
    __syncthreads();

    const u16* fb = (lvl == 0) ? (tf0 + (size_t)b * 16384 * 256)
                  : (lvl == 1) ? (tf1 + (size_t)b * 4096 * 256)
                               : (tf2 + (size_t)b * 1024 * 256);
    int g = tid >> 5;
    int c0 = (tid & 31) * 8;
    u16* xr = xb + (size_t)bn * 12544;

    for (int ii = 0; ii < 7; ++ii) {
        int bin = g + ii * 8;
        if (bin >= 49) break;
        int ph = bin / 7, pw = bin % 7;
        float a[8] = {0.f, 0.f, 0.f, 0.f, 0.f, 0.f, 0.f, 0.f};
        #pragma unroll
        for (int dy = 0; dy < SR; ++dy) {
            #pragma unroll
            for (int dx = 0; dx < SR; ++dx) {
                int si = (ph * SR + dy) * SS + (pw * SR + dx);
                int o00 = s_o00[si], o01 = s_o01[si];
                int o10 = s_o10[si], o11 = s_o11[si];
                float w00 = s_w00[si], w01 = s_w01[si];
                float w10 = s_w10[si], w11 = s_w11[si];
                union { uint4 v; u16 h[8]; } u0, u1, u2, u3;
                u0.v = *(const uint4*)(fb + o00 + c0);
                u1.v = *(const uint4*)(fb + o01 + c0);
                u2.v = *(const uint4*)(fb + o10 + c0);
                u3.v = *(const uint4*)(fb + o11 + c0);
                #pragma unroll
                for (int j = 0; j < 8; ++j) {
                    a[j] = fmaf(bf2f(u0.h[j]), w00, a[j]);
                    a[j] = fmaf(bf2f(u1.h[j]), w01, a[j]);
                    a[j] = fmaf(bf2f(u2.h[j]), w10, a[j]);
                    a[j] = fmaf(bf2f(u3.h[j]), w11, a[j]);
                }
            }
        }
        union { uint4 v; u16 h[8]; } o;
        #pragma unroll
        for (int j = 0; j < 8; ++j) o.h[j] = f2bf(a[j]);
        *(uint4*)&xr[bin * 256 + c0] = o.v;
    }
}

// ---------------------------------------------------------------------------
// bf16 MFMA GEMM: C(M,N) = A(M,K) @ BT(N,K)^T + bias
// 64x64 tile, BK=32, 4 waves; wave w: rows [16w,16w+16), 4 n-tiles.
// D layout: col=lane&15, row=(lane>>4)*4+reg  (m89-verified)
// ---------------------------------------------------------------------------
#define LDSTR 40  // padded LDS row stride in u16 (80B rows: 16B aligned)

__global__ __launch_bounds__(256) void gemm_bt_kernel(
    const u16* __restrict__ A, const u16* __restrict__ BT,
    const float* __restrict__ bias, float* __restrict__ Cout,
    int M, int N, int K) {
    __shared__ u16 la[64 * LDSTR];
    __shared__ u16 lb[64 * LDSTR];
    int m0 = blockIdx.x * 64;
    int n0 = blockIdx.y * 64;
    int tid = threadIdx.x;
    int wave = tid >> 6, lane = tid & 63;

    f32x4 acc[4] = {};

    int rr = tid >> 2, kq = (tid & 3) * 8;
    const u16* Ap = A + (size_t)(m0 + rr) * K + kq;
    const u16* Bp = BT + (size_t)(n0 + rr) * K + kq;

    for (int k0 = 0; k0 < K; k0 += 32) {
        uint4 av = *(const uint4*)(Ap + k0);
        uint4 bv = *(const uint4*)(Bp + k0);
        *(uint4*)&la[rr * LDSTR + kq] = av;
        *(uint4*)&lb[rr * LDSTR + kq] = bv;
        __syncthreads();

        bf16x8 af = *(const bf16x8*)&la[(wave * 16 + (lane & 15)) * LDSTR + (lane >> 4) * 8];
        #pragma unroll
        for (int tn = 0; tn < 4; ++tn) {
            bf16x8 bf = *(const bf16x8*)&lb[(tn * 16 + (lane & 15)) * LDSTR + (lane >> 4) * 8];
            acc[tn] = __builtin_amdgcn_mfma_f32_16x16x32_bf16(af, bf, acc[tn], 0, 0, 0);
        }
        __syncthreads();
    }

    int col = lane & 15, rquad = lane >> 4;
    #pragma unroll
    for (int tn = 0; tn < 4; ++tn) {
        int nn = n0 + tn * 16 + col;
        float bs = bias[nn];
        #pragma unroll
        for (int rg = 0; rg < 4; ++rg) {
            int mm = m0 + wave * 16 + rquad * 4 + rg;
            Cout[(size_t)mm * N + nn] = acc[tn][rg] + bs;
        }
    }
}

// ---------------------------------------------------------------------------
// BN stats: per-column mean & rstd over M rows
// ---------------------------------------------------------------------------
__global__ __launch_bounds__(256) void bn_stats_kernel(
    const float* __restrict__ y, float* __restrict__ stats, int M, int N) {
    int cx = threadIdx.x & 63, rg = threadIdx.x >> 6;
    int col = blockIdx.x * 64 + cx;
    float s = 0.f, sq = 0.f;
    for (int r = rg; r < M; r += 4) {
        float v = y[(size_t)r * N + col];
        s += v; sq += v * v;
    }
    __shared__ float ls[4][64], lq[4][64];
    ls[rg][cx] = s; lq[rg][cx] = sq;
    __syncthreads();
    if (rg == 0) {
        s = ls[0][cx] + ls[1][cx] + ls[2][cx] + ls[3][cx];
        sq = lq[0][cx] + lq[1][cx] + lq[2][cx] + lq[3][cx];
        float mean = s / (float)M;
        float var = sq / (float)M - mean * mean;
        stats[col] = mean;
        stats[N + col] = rsqrtf(var + 1e-5f);
    }
}

// ---------------------------------------------------------------------------
// BN apply + relu -> bf16.  N hardcoded 1024.
// ---------------------------------------------------------------------------
__global__ void bn_apply_kernel(const float* __restrict__ y,
                                const float* __restrict__ stats,
                                const float* __restrict__ g,
                                const float* __restrict__ b,
                                __hip_bfloat16* __restrict__ xo, int total) {
    int idx = blockIdx.x * blockDim.x + threadIdx.x;
    if (idx >= total) return;
    int col = idx & 1023;
    float v = (y[idx] - stats[col]) * stats[1024 + col] * g[col] + b[col];
    xo[idx] = __float2bfloat16(fmaxf(v, 0.f));
}

// ---------------------------------------------------------------------------
// heads: out(2048,100) = x(2048,1024)bf16 @ wh(1024,100)f32 + bh
// ---------------------------------------------------------------------------
__global__ __launch_bounds__(128) void heads_kernel(
    const __hip_bfloat16* __restrict__ x, const float* __restrict__ wh,
    const float* __restrict__ bh, float* __restrict__ out) {
    int m = blockIdx.x;
    __shared__ float lx[1024];
    for (int k = threadIdx.x; k < 1024; k += 128)
        lx[k] = __bfloat162float(x[(size_t)m * 1024 + k]);
    __syncthreads();
    int n = threadIdx.x;
    if (n < 100) {
        float acc = bh[n];
        for (int k = 0; k < 1024; ++k)
            acc += lx[k] * wh[k * 100 + n];
        out[(size_t)m * 100 + n] = acc;
    }
}

// ---------------------------------------------------------------------------
extern "C" void kernel_launch(void* const* d_in, const int* in_sizes, int n_in,
                              void* d_out, int out_size, void* d_ws, size_t ws_size,
                              hipStream_t stream) {
    const float* feat0   = (const float*)d_in[0];
    const float* feat1   = (const float*)d_in[1];
    const float* feat2   = (const float*)d_in[2];
    const float* bbox2d  = (const float*)d_in[3];
    const int*   anchor  = (const int*)d_in[4];
    const float* fc1_w   = (const float*)d_in[5];
    const float* fc1_b   = (const float*)d_in[6];
    const float* bn1_g   = (const float*)d_in[7];
    const float* bn1_b   = (const float*)d_in[8];
    const float* fc2_w   = (const float*)d_in[9];
    const float* fc2_b   = (const float*)d_in[10];
    const float* bn2_g   = (const float*)d_in[11];
    const float* bn2_b   = (const float*)d_in[12];
    const float* cate_w  = (const float*)d_in[13];
    const float* cate_b  = (const float*)d_in[14];
    const float* bbox3d_w= (const float*)d_in[15];
    const float* bbox3d_b= (const float*)d_in[16];
    const float* yawc_w  = (const float*)d_in[17];
    const float* yawc_b  = (const float*)d_in[18];
    const float* yawr_w  = (const float*)d_in[19];
    const float* yawr_b  = (const float*)d_in[20];
    const float* hgt_w   = (const float*)d_in[21];
    const float* hgt_b   = (const float*)d_in[22];

    const int B = 4, N = 512, FC = 1024;
    const int M = B * N;   // 2048
    const int K1 = 12544;  // 256*49

    // workspace layout (tf* region aliased with post-ROI buffers; lifetimes
    // are disjoint: tf* dead once roi_align_v2 completes, w1t/w2t/y/x1b live
    // only after it)
    char* base = (char*)d_ws;
    u16* xb = (u16*)base;                              // 51,380,224 B
    char* ub = base + 51380224;                        // union, 44,040,192 B
    u16* tf0 = (u16*)ub;                               // 33,554,432
    u16* tf1 = (u16*)(ub + 33554432);                  //  8,388,608
    u16* tf2 = (u16*)(ub + 41943040);                  //  2,097,152
    u16* w1t = (u16*)ub;                               // 25,690,112
    u16* w2t = (u16*)(ub + 25690112);                  //  2,097,152
    float* y   = (float*)(ub + 27787264);              //  8,388,608
    u16* x1b = (u16*)(ub + 36175872);                  //  4,194,304  (end 40,370,176)
    char* tail = ub + 44040192;
    float* stats = (float*)tail;                       // 8 KB
    float* wh    = (float*)(tail + 8192);              // 409,600
    float* bhd   = (float*)(tail + 8192 + 409600);     // 512
    float* outp  = (float*)d_out;

    // 1. head weight concat (independent)
    head_concat_kernel<<<(1024 * 100 + 255) / 256, 256, 0, stream>>>(
        cate_w, bbox3d_w, yawc_w, yawr_w, hgt_w,
        cate_b, bbox3d_b, yawc_b, yawr_b, hgt_b, wh, bhd);

    // 2. feature layout transform (B,C,H,W)f32 -> (B,HW,C)bf16
    transpose_feat_kernel<<<dim3(16384 / 64, B), 256, 0, stream>>>(feat0, tf0, 16384);
    transpose_feat_kernel<<<dim3(4096 / 64, B),  256, 0, stream>>>(feat1, tf1, 4096);
    transpose_feat_kernel<<<dim3(1024 / 64, B),  256, 0, stream>>>(feat2, tf2, 1024);

    // 3. ROI align -> x bf16 (M, K1), k' = bin*256 + c layout
    roi_align_v2_kernel<<<M, 256, 0, stream>>>(tf0, tf1, tf2, bbox2d, anchor, xb);

    // 4. weight transposes (after roi: they overwrite the tf* region)
    transpose_w_kernel<<<dim3(K1 / 64, FC / 64), 256, 0, stream>>>(fc1_w, w1t, K1, 1);
    transpose_w_kernel<<<dim3(FC / 64, FC / 64), 256, 0, stream>>>(fc2_w, w2t, FC, 0);

    // 5. fc1 + BN1
    gemm_bt_kernel<<<dim3(M / 64, FC / 64), 256, 0, stream>>>(xb, w1t, fc1_b, y, M, FC, K1);
    bn_stats_kernel<<<FC / 64, 256, 0, stream>>>(y, stats, M, FC);
    bn_apply_kernel<<<(M * FC + 255) / 256, 256, 0, stream>>>(
        y, stats, bn1_g, bn1_b, (__hip_bfloat16*)x1b, M * FC);

    // 6. fc2 + BN2
    gemm_bt_kernel<<<dim3(M / 64, FC / 64), 256, 0, stream>>>(x1b, w2t, fc2_b, y, M, FC, FC);
    bn_stats_kernel<<<FC / 64, 256, 0, stream>>>(y, stats, M, FC);
    bn_apply_kernel<<<(M * FC + 255) / 256, 256, 0, stream>>>(
        y, stats, bn2_g, bn2_b, (__hip_bfloat16*)x1b, M * FC);

    // 7. heads -> d_out
    heads_kernel<<<M, 128, 0, stream>>>((const __hip_bfloat16*)x1b, wh, bhd, outp);
}

// Round 3
// 774.174 us; speedup vs baseline: 3.1732x; 1.0685x over previous
//
#include <hip/hip_runtime.h>
#include <hip/hip_bf16.h>

typedef unsigned short u16;
typedef unsigned int u32;
typedef __bf16 bf16x8 __attribute__((ext_vector_type(8)));
typedef float f32x4 __attribute__((ext_vector_type(4)));

#define RESOLUTION 7
#define SR 2
#define SS 14
#define NSAMP 196

static __device__ __forceinline__ u16 f2bf(float f) {
    __hip_bfloat16 t = __float2bfloat16(f);
    return *reinterpret_cast<u16*>(&t);
}
static __device__ __forceinline__ float bf2f(u16 h) {
    return __uint_as_float(((u32)h) << 16);
}

// async global->LDS, 16B per lane; lds ptr must be wave-uniform (dest =
// base + lane*16)  [m97/m104-verified pattern]
static __device__ __forceinline__ void load_lds16(const u16* g, u16* l) {
    __builtin_amdgcn_global_load_lds(
        (const __attribute__((address_space(1))) unsigned int*)g,
        (__attribute__((address_space(3))) unsigned int*)l, 16, 0, 0);
}

// ---------------------------------------------------------------------------
// feat (B,C,H,W) f32  ->  (B,HW,C) bf16.  C=256.
// ---------------------------------------------------------------------------
__global__ __launch_bounds__(256) void transpose_feat_kernel(
    const float* __restrict__ in, u16* __restrict__ out, int HW) {
    int b = blockIdx.y;
    int hw0 = blockIdx.x * 64;
    __shared__ u16 tile[256][65];

    int hwo = threadIdx.x & 63;
    int c0 = threadIdx.x >> 6;
    for (int cc = 0; cc < 256; cc += 4) {
        int c = cc + c0;
        float v = in[((size_t)(b * 256 + c)) * HW + hw0 + hwo];
        tile[c][hwo] = f2bf(v);
    }
    __syncthreads();

    int ro = threadIdx.x >> 5;
    int co = (threadIdx.x & 31) * 8;
    for (int i = 0; i < 64; i += 8) {
        int hw = i + ro;
        union { uint4 v; u16 h[8]; } o;
        #pragma unroll
        for (int j = 0; j < 8; ++j) o.h[j] = tile[co + j][hw];
        *(uint4*)&out[((size_t)b * HW + hw0 + hw) * 256 + co] = o.v;
    }
}

// ---------------------------------------------------------------------------
// weight transpose: out (N=1024, K) bf16 = in (K, 1024) f32,
// optional k-permutation  k = (kp&255)*49 + (kp>>8)
// ---------------------------------------------------------------------------
__global__ __launch_bounds__(256) void transpose_w_kernel(
    const float* __restrict__ in, u16* __restrict__ out, int K, int perm) {
    int kp0 = blockIdx.x * 64, n0 = blockIdx.y * 64;
    __shared__ u16 tile[64][65];

    int nn = threadIdx.x & 63, ks = threadIdx.x >> 6;
    for (int i = 0; i < 64; i += 4) {
        int kp = kp0 + ks + i;
        int k = perm ? ((kp & 255) * 49 + (kp >> 8)) : kp;
        tile[ks + i][nn] = f2bf(in[(size_t)k * 1024 + n0 + nn]);
    }
    __syncthreads();

    int nw = threadIdx.x >> 3, ko = (threadIdx.x & 7) * 8;
    for (int i = 0; i < 2; ++i) {
        int n = nw + i * 32;
        union { uint4 v; u16 h[8]; } o;
        #pragma unroll
        for (int j = 0; j < 8; ++j) o.h[j] = tile[ko + j][n];
        *(uint4*)&out[(size_t)(n0 + n) * K + kp0 + ko] = o.v;
    }
}

// ---------------------------------------------------------------------------
// concat head weights (1024 x 100) + bias (100)
// ---------------------------------------------------------------------------
__global__ void head_concat_kernel(
    const float* __restrict__ cate_w, const float* __restrict__ bbox3d_w,
    const float* __restrict__ yawc_w, const float* __restrict__ yawr_w,
    const float* __restrict__ hgt_w,
    const float* __restrict__ cate_b, const float* __restrict__ bbox3d_b,
    const float* __restrict__ yawc_b, const float* __restrict__ yawr_b,
    const float* __restrict__ hgt_b,
    float* __restrict__ wh, float* __restrict__ bh) {
    int idx = blockIdx.x * blockDim.x + threadIdx.x;
    if (idx < 1024 * 100) {
        int k = idx / 100, c = idx % 100;
        float v;
        if (c < 4)        v = cate_w[k * 4 + c];
        else if (c < 22)  v = bbox3d_w[k * 18 + (c - 4)];
        else if (c < 58)  v = yawc_w[k * 36 + (c - 22)];
        else if (c < 94)  v = yawr_w[k * 36 + (c - 58)];
        else              v = hgt_w[k * 6 + (c - 94)];
        wh[idx] = v;
    }
    if (idx < 100) {
        int c = idx;
        float v;
        if (c < 4)        v = cate_b[c];
        else if (c < 22)  v = bbox3d_b[c - 4];
        else if (c < 58)  v = yawc_b[c - 22];
        else if (c < 94)  v = yawr_b[c - 58];
        else              v = hgt_b[c - 94];
        bh[c] = v;
    }
}

// ---------------------------------------------------------------------------
// ROI align v2 on (B,HW,C) bf16 feats.  x row layout: k' = bin*256 + c.
// ---------------------------------------------------------------------------
__global__ __launch_bounds__(256) void roi_align_v2_kernel(
    const u16* __restrict__ tf0, const u16* __restrict__ tf1,
    const u16* __restrict__ tf2, const float* __restrict__ bbox2d,
    const int* __restrict__ anchor_id, u16* __restrict__ xb) {
    int bn = blockIdx.x;
    int b = bn >> 9;
    int tid = threadIdx.x;

    __shared__ int s_o00[NSAMP], s_o01[NSAMP], s_o10[NSAMP], s_o11[NSAMP];
    __shared__ float s_w00[NSAMP], s_w01[NSAMP], s_w10[NSAMP], s_w11[NSAMP];

    float cy = bbox2d[bn * 4 + 0], cx = bbox2d[bn * 4 + 1];
    float hh = bbox2d[bn * 4 + 2], ww = bbox2d[bn * 4 + 3];
    int lvl = anchor_id[bn] / 3;
    float scale = (lvl == 0) ? 0.25f : ((lvl == 1) ? 0.125f : 0.0625f);
    int H = (lvl == 0) ? 128 : ((lvl == 1) ? 64 : 32);
    int W = H;

    float t = cy - hh * 0.5f, l = cx - ww * 0.5f;
    float btm = cy + hh * 0.5f, r = cx + ww * 0.5f;
    float sy = t * scale - 0.5f, sx = l * scale - 0.5f;
    float bh = (btm - t) * scale * (1.0f / RESOLUTION);
    float bw = (r - l) * scale * (1.0f / RESOLUTION);

    if (tid < NSAMP) {
        int i = tid / SS, j = tid % SS;
        float gi = (i + 0.5f) * (1.0f / SR);
        float gj = (j + 0.5f) * (1.0f / SR);
        float y = sy + gi * bh, x = sx + gj * bw;
        float valid = (y > -1.0f && y < (float)H && x > -1.0f && x < (float)W)
                          ? 0.25f : 0.0f;
        y = fminf(fmaxf(y, 0.0f), (float)(H - 1));
        x = fminf(fmaxf(x, 0.0f), (float)(W - 1));
        int y0 = (int)floorf(y), x0 = (int)floorf(x);
        int y1 = min(y0 + 1, H - 1), x1 = min(x0 + 1, W - 1);
        float ly = y - (float)y0, lx = x - (float)x0;
        float hy = 1.f - ly, hx = 1.f - lx;
        s_o00[tid] = (y0 * W + x0) * 256;
        s_o01[tid] = (y0 * W + x1) * 256;
        s_o10[tid] = (y1 * W + x0) * 256;
        s_o11[tid] = (y1 * W + x1) * 256;
        s_w00[tid] = hy * hx * valid;
        s_w01[tid] = hy * lx * valid;
        s_w10[tid] = ly * hx * valid;
        s_w11[tid] = ly * lx * valid;
    }
    __syncthreads();

    const u16* fb = (lvl == 0) ? (tf0 + (size_t)b * 16384 * 256)
                  : (lvl == 1) ? (tf1 + (size_t)b * 4096 * 256)
                               : (tf2 + (size_t)b * 1024 * 256);
    int g = tid >> 5;
    int c0 = (tid & 31) * 8;
    u16* xr = xb + (size_t)bn * 12544;

    for (int ii = 0; ii < 7; ++ii) {
        int bin = g + ii * 8;
        if (bin >= 49) break;
        int ph = bin / 7, pw = bin % 7;
        float a[8] = {0.f, 0.f, 0.f, 0.f, 0.f, 0.f, 0.f, 0.f};
        #pragma unroll
        for (int dy = 0; dy < SR; ++dy) {
            #pragma unroll
            for (int dx = 0; dx < SR; ++dx) {
                int si = (ph * SR + dy) * SS + (pw * SR + dx);
                int o00 = s_o00[si], o01 = s_o01[si];
                int o10 = s_o10[si], o11 = s_o11[si];
                float w00 = s_w00[si], w01 = s_w01[si];
                float w10 = s_w10[si], w11 = s_w11[si];
                union { uint4 v; u16 h[8]; } u0, u1, u2, u3;
                u0.v = *(const uint4*)(fb + o00 + c0);
                u1.v = *(const uint4*)(fb + o01 + c0);
                u2.v = *(const uint4*)(fb + o10 + c0);
                u3.v = *(const uint4*)(fb + o11 + c0);
                #pragma unroll
                for (int j = 0; j < 8; ++j) {
                    a[j] = fmaf(bf2f(u0.h[j]), w00, a[j]);
                    a[j] = fmaf(bf2f(u1.h[j]), w01, a[j]);
                    a[j] = fmaf(bf2f(u2.h[j]), w10, a[j]);
                    a[j] = fmaf(bf2f(u3.h[j]), w11, a[j]);
                }
            }
        }
        union { uint4 v; u16 h[8]; } o;
        #pragma unroll
        for (int j = 0; j < 8; ++j) o.h[j] = f2bf(a[j]);
        *(uint4*)&xr[bin * 256 + c0] = o.v;
    }
}

// ---------------------------------------------------------------------------
// zero fill (float4)
// ---------------------------------------------------------------------------
__global__ void zero_kernel(float4* __restrict__ p, int n4) {
    int idx = blockIdx.x * blockDim.x + threadIdx.x;
    if (idx < n4) p[idx] = make_float4(0.f, 0.f, 0.f, 0.f);
}

// ---------------------------------------------------------------------------
// m97-style 128x128 MFMA GEMM with split-K + atomic accumulation.
// Y(M,N) += A(M,K-chunk) @ BT(N,K-chunk)^T    (Y pre-zeroed; no bias — fc
// biases cancel in BN)
// 256 thr = 4 waves in 2x2 quadrants; wave: 4x4 grid of 16x16x32 MFMA.
// LDS row-major 128x32 (layout forced by global_load_lds lane ordering).
// ---------------------------------------------------------------------------
__global__ __launch_bounds__(256) void gemm_splitk_kernel(
    const u16* __restrict__ A, const u16* __restrict__ BT,
    float* __restrict__ Y, int M, int N, int K, int KC) {
    __shared__ u16 la[128 * 32];
    __shared__ u16 lb[128 * 32];
    int m0 = blockIdx.x * 128;
    int n0 = blockIdx.y * 128;
    int kbeg = blockIdx.z * KC;
    int tid = threadIdx.x;
    int w = tid >> 6, lane = tid & 63;
    int wm = (w >> 1) * 64, wn = (w & 1) * 64;

    // staging: chunk idx0 = tid covers rows 0..63, idx1 = tid+256 rows 64..127
    int idx1 = tid + 256;
    const u16* gA0 = A + (size_t)(m0 + (tid >> 2)) * K + (tid & 3) * 8 + kbeg;
    const u16* gA1 = A + (size_t)(m0 + (idx1 >> 2)) * K + (idx1 & 3) * 8 + kbeg;
    const u16* gB0 = BT + (size_t)(n0 + (tid >> 2)) * K + (tid & 3) * 8 + kbeg;
    const u16* gB1 = BT + (size_t)(n0 + (idx1 >> 2)) * K + (idx1 & 3) * 8 + kbeg;
    u16* lA0 = la + w * 512;          // wave-uniform LDS bases
    u16* lA1 = la + 2048 + w * 512;
    u16* lB0 = lb + w * 512;
    u16* lB1 = lb + 2048 + w * 512;

    f32x4 acc[4][4] = {};
    int row16 = lane & 15, q8 = (lane >> 4) * 8;

    for (int k0 = 0; k0 < KC; k0 += 32) {
        load_lds16(gA0 + k0, lA0);
        load_lds16(gA1 + k0, lA1);
        load_lds16(gB0 + k0, lB0);
        load_lds16(gB1 + k0, lB1);
        __syncthreads();  // compiler emits vmcnt(0) drain before barrier

        bf16x8 af[4], bf[4];
        #pragma unroll
        for (int tm = 0; tm < 4; ++tm)
            af[tm] = *(const bf16x8*)&la[(wm + tm * 16 + row16) * 32 + q8];
        #pragma unroll
        for (int tn = 0; tn < 4; ++tn)
            bf[tn] = *(const bf16x8*)&lb[(wn + tn * 16 + row16) * 32 + q8];
        #pragma unroll
        for (int tm = 0; tm < 4; ++tm)
            #pragma unroll
            for (int tn = 0; tn < 4; ++tn)
                acc[tm][tn] = __builtin_amdgcn_mfma_f32_16x16x32_bf16(
                    af[tm], bf[tn], acc[tm][tn], 0, 0, 0);
        __syncthreads();
    }

    // D layout: col=lane&15, row=(lane>>4)*4+reg  (m89-verified)
    int col = lane & 15, qr = lane >> 4;
    #pragma unroll
    for (int tm = 0; tm < 4; ++tm) {
        #pragma unroll
        for (int tn = 0; tn < 4; ++tn) {
            int nn = n0 + wn + tn * 16 + col;
            #pragma unroll
            for (int rg = 0; rg < 4; ++rg) {
                int mm = m0 + wm + tm * 16 + qr * 4 + rg;
                unsafeAtomicAdd(&Y[(size_t)mm * N + nn], acc[tm][tn][rg]);
            }
        }
    }
}

// ---------------------------------------------------------------------------
// BN stats: per-column mean & rstd over M rows
// ---------------------------------------------------------------------------
__global__ __launch_bounds__(256) void bn_stats_kernel(
    const float* __restrict__ y, float* __restrict__ stats, int M, int N) {
    int cx = threadIdx.x & 63, rg = threadIdx.x >> 6;
    int col = blockIdx.x * 64 + cx;
    float s = 0.f, sq = 0.f;
    for (int r = rg; r < M; r += 4) {
        float v = y[(size_t)r * N + col];
        s += v; sq += v * v;
    }
    __shared__ float ls[4][64], lq[4][64];
    ls[rg][cx] = s; lq[rg][cx] = sq;
    __syncthreads();
    if (rg == 0) {
        s = ls[0][cx] + ls[1][cx] + ls[2][cx] + ls[3][cx];
        sq = lq[0][cx] + lq[1][cx] + lq[2][cx] + lq[3][cx];
        float mean = s / (float)M;
        float var = sq / (float)M - mean * mean;
        stats[col] = mean;
        stats[N + col] = rsqrtf(var + 1e-5f);
    }
}

// ---------------------------------------------------------------------------
// BN apply + relu -> bf16.  N hardcoded 1024.
// ---------------------------------------------------------------------------
__global__ void bn_apply_kernel(const float* __restrict__ y,
                                const float* __restrict__ stats,
                                const float* __restrict__ g,
                                const float* __restrict__ b,
                                __hip_bfloat16* __restrict__ xo, int total) {
    int idx = blockIdx.x * blockDim.x + threadIdx.x;
    if (idx >= total) return;
    int col = idx & 1023;
    float v = (y[idx] - stats[col]) * stats[1024 + col] * g[col] + b[col];
    xo[idx] = __float2bfloat16(fmaxf(v, 0.f));
}

// ---------------------------------------------------------------------------
// heads: out(2048,100) = x(2048,1024)bf16 @ wh(1024,100)f32 + bh
// ---------------------------------------------------------------------------
__global__ __launch_bounds__(128) void heads_kernel(
    const __hip_bfloat16* __restrict__ x, const float* __restrict__ wh,
    const float* __restrict__ bh, float* __restrict__ out) {
    int m = blockIdx.x;
    __shared__ float lx[1024];
    for (int k = threadIdx.x; k < 1024; k += 128)
        lx[k] = __bfloat162float(x[(size_t)m * 1024 + k]);
    __syncthreads();
    int n = threadIdx.x;
    if (n < 100) {
        float acc = bh[n];
        for (int k = 0; k < 1024; ++k)
            acc += lx[k] * wh[k * 100 + n];
        out[(size_t)m * 100 + n] = acc;
    }
}

// ---------------------------------------------------------------------------
extern "C" void kernel_launch(void* const* d_in, const int* in_sizes, int n_in,
                              void* d_out, int out_size, void* d_ws, size_t ws_size,
                              hipStream_t stream) {
    const float* feat0   = (const float*)d_in[0];
    const float* feat1   = (const float*)d_in[1];
    const float* feat2   = (const float*)d_in[2];
    const float* bbox2d  = (const float*)d_in[3];
    const int*   anchor  = (const int*)d_in[4];
    const float* fc1_w   = (const float*)d_in[5];
    const float* bn1_g   = (const float*)d_in[7];
    const float* bn1_b   = (const float*)d_in[8];
    const float* fc2_w   = (const float*)d_in[9];
    const float* bn2_g   = (const float*)d_in[11];
    const float* bn2_b   = (const float*)d_in[12];
    const float* cate_w  = (const float*)d_in[13];
    const float* cate_b  = (const float*)d_in[14];
    const float* bbox3d_w= (const float*)d_in[15];
    const float* bbox3d_b= (const float*)d_in[16];
    const float* yawc_w  = (const float*)d_in[17];
    const float* yawc_b  = (const float*)d_in[18];
    const float* yawr_w  = (const float*)d_in[19];
    const float* yawr_b  = (const float*)d_in[20];
    const float* hgt_w   = (const float*)d_in[21];
    const float* hgt_b   = (const float*)d_in[22];

    const int B = 4, N = 512, FC = 1024;
    const int M = B * N;   // 2048
    const int K1 = 12544;  // 256*49

    // workspace layout (tf* aliased with post-ROI buffers; disjoint lifetimes)
    char* base = (char*)d_ws;
    u16* xb = (u16*)base;                              // 51,380,224 B
    char* ub = base + 51380224;                        // union, 44,040,192 B
    u16* tf0 = (u16*)ub;                               // 33,554,432
    u16* tf1 = (u16*)(ub + 33554432);                  //  8,388,608
    u16* tf2 = (u16*)(ub + 41943040);                  //  2,097,152
    u16* w1t = (u16*)ub;                               // 25,690,112
    u16* w2t = (u16*)(ub + 25690112);                  //  2,097,152
    float* y   = (float*)(ub + 27787264);              //  8,388,608
    u16* x1b = (u16*)(ub + 36175872);                  //  4,194,304
    char* tail = ub + 44040192;
    float* stats = (float*)tail;                       // 8 KB
    float* wh    = (float*)(tail + 8192);              // 409,600
    float* bhd   = (float*)(tail + 8192 + 409600);     // 512
    float* outp  = (float*)d_out;

    // 1. head weight concat (independent)
    head_concat_kernel<<<(1024 * 100 + 255) / 256, 256, 0, stream>>>(
        cate_w, bbox3d_w, yawc_w, yawr_w, hgt_w,
        cate_b, bbox3d_b, yawc_b, yawr_b, hgt_b, wh, bhd);

    // 2. feature layout transform (B,C,H,W)f32 -> (B,HW,C)bf16
    transpose_feat_kernel<<<dim3(16384 / 64, B), 256, 0, stream>>>(feat0, tf0, 16384);
    transpose_feat_kernel<<<dim3(4096 / 64, B),  256, 0, stream>>>(feat1, tf1, 4096);
    transpose_feat_kernel<<<dim3(1024 / 64, B),  256, 0, stream>>>(feat2, tf2, 1024);

    // 3. ROI align -> x bf16 (M, K1), k' = bin*256 + c layout
    roi_align_v2_kernel<<<M, 256, 0, stream>>>(tf0, tf1, tf2, bbox2d, anchor, xb);

    // 4. weight transposes (overwrite tf* region — after roi)
    transpose_w_kernel<<<dim3(K1 / 64, FC / 64), 256, 0, stream>>>(fc1_w, w1t, K1, 1);
    transpose_w_kernel<<<dim3(FC / 64, FC / 64), 256, 0, stream>>>(fc2_w, w2t, FC, 0);

    // 5. fc1 (split-K=4, atomic accumulate into zeroed y) + BN1
    zero_kernel<<<(M * FC / 4 + 255) / 256, 256, 0, stream>>>((float4*)y, M * FC / 4);
    gemm_splitk_kernel<<<dim3(M / 128, FC / 128, 4), 256, 0, stream>>>(
        xb, w1t, y, M, FC, K1, K1 / 4);
    bn_stats_kernel<<<FC / 64, 256, 0, stream>>>(y, stats, M, FC);
    bn_apply_kernel<<<(M * FC + 255) / 256, 256, 0, stream>>>(
        y, stats, bn1_g, bn1_b, (__hip_bfloat16*)x1b, M * FC);

    // 6. fc2 (split-K=4) + BN2
    zero_kernel<<<(M * FC / 4 + 255) / 256, 256, 0, stream>>>((float4*)y, M * FC / 4);
    gemm_splitk_kernel<<<dim3(M / 128, FC / 128, 4), 256, 0, stream>>>(
        x1b, w2t, y, M, FC, FC, FC / 4);
    bn_stats_kernel<<<FC / 64, 256, 0, stream>>>(y, stats, M, FC);
    bn_apply_kernel<<<(M * FC + 255) / 256, 256, 0, stream>>>(
        y, stats, bn2_g, bn2_b, (__hip_bfloat16*)x1b, M * FC);

    // 7. heads -> d_out
    heads_kernel<<<M, 128, 0, stream>>>((const __hip_bfloat16*)x1b, wh, bhd, outp);
}

// Round 4
// 504.899 us; speedup vs baseline: 4.8655x; 1.5333x over previous
//
#include <hip/hip_runtime.h>
#include <hip/hip_bf16.h>

typedef unsigned short u16;
typedef unsigned int u32;
typedef __bf16 bf16x8 __attribute__((ext_vector_type(8)));
typedef float f32x4 __attribute__((ext_vector_type(4)));

#define RESOLUTION 7
#define SR 2
#define SS 14
#define NSAMP 196

static __device__ __forceinline__ u16 f2bf(float f) {
    __hip_bfloat16 t = __float2bfloat16(f);
    return *reinterpret_cast<u16*>(&t);
}
static __device__ __forceinline__ float bf2f(u16 h) {
    return __uint_as_float(((u32)h) << 16);
}

// async global->LDS, 16B per lane; lds ptr must be wave-uniform (dest =
// base + lane*16)  [m97/m104-verified pattern]
static __device__ __forceinline__ void load_lds16(const u16* g, u16* l) {
    __builtin_amdgcn_global_load_lds(
        (const __attribute__((address_space(1))) unsigned int*)g,
        (__attribute__((address_space(3))) unsigned int*)l, 16, 0, 0);
}

// ---------------------------------------------------------------------------
// feat (B,C,H,W) f32  ->  (B,HW,C) bf16.  C=256.
// ---------------------------------------------------------------------------
__global__ __launch_bounds__(256) void transpose_feat_kernel(
    const float* __restrict__ in, u16* __restrict__ out, int HW) {
    int b = blockIdx.y;
    int hw0 = blockIdx.x * 64;
    __shared__ u16 tile[256][65];

    int hwo = threadIdx.x & 63;
    int c0 = threadIdx.x >> 6;
    for (int cc = 0; cc < 256; cc += 4) {
        int c = cc + c0;
        float v = in[((size_t)(b * 256 + c)) * HW + hw0 + hwo];
        tile[c][hwo] = f2bf(v);
    }
    __syncthreads();

    int ro = threadIdx.x >> 5;
    int co = (threadIdx.x & 31) * 8;
    for (int i = 0; i < 64; i += 8) {
        int hw = i + ro;
        union { uint4 v; u16 h[8]; } o;
        #pragma unroll
        for (int j = 0; j < 8; ++j) o.h[j] = tile[co + j][hw];
        *(uint4*)&out[((size_t)b * HW + hw0 + hw) * 256 + co] = o.v;
    }
}

// ---------------------------------------------------------------------------
// weight transpose: out (N=1024, K) bf16 = in (K, 1024) f32,
// optional k-permutation  k = (kp&255)*49 + (kp>>8)
// ---------------------------------------------------------------------------
__global__ __launch_bounds__(256) void transpose_w_kernel(
    const float* __restrict__ in, u16* __restrict__ out, int K, int perm) {
    int kp0 = blockIdx.x * 64, n0 = blockIdx.y * 64;
    __shared__ u16 tile[64][65];

    int nn = threadIdx.x & 63, ks = threadIdx.x >> 6;
    for (int i = 0; i < 64; i += 4) {
        int kp = kp0 + ks + i;
        int k = perm ? ((kp & 255) * 49 + (kp >> 8)) : kp;
        tile[ks + i][nn] = f2bf(in[(size_t)k * 1024 + n0 + nn]);
    }
    __syncthreads();

    int nw = threadIdx.x >> 3, ko = (threadIdx.x & 7) * 8;
    for (int i = 0; i < 2; ++i) {
        int n = nw + i * 32;
        union { uint4 v; u16 h[8]; } o;
        #pragma unroll
        for (int j = 0; j < 8; ++j) o.h[j] = tile[ko + j][n];
        *(uint4*)&out[(size_t)(n0 + n) * K + kp0 + ko] = o.v;
    }
}

// ---------------------------------------------------------------------------
// concat head weights (1024 x 100) + bias (100)
// ---------------------------------------------------------------------------
__global__ void head_concat_kernel(
    const float* __restrict__ cate_w, const float* __restrict__ bbox3d_w,
    const float* __restrict__ yawc_w, const float* __restrict__ yawr_w,
    const float* __restrict__ hgt_w,
    const float* __restrict__ cate_b, const float* __restrict__ bbox3d_b,
    const float* __restrict__ yawc_b, const float* __restrict__ yawr_b,
    const float* __restrict__ hgt_b,
    float* __restrict__ wh, float* __restrict__ bh) {
    int idx = blockIdx.x * blockDim.x + threadIdx.x;
    if (idx < 1024 * 100) {
        int k = idx / 100, c = idx % 100;
        float v;
        if (c < 4)        v = cate_w[k * 4 + c];
        else if (c < 22)  v = bbox3d_w[k * 18 + (c - 4)];
        else if (c < 58)  v = yawc_w[k * 36 + (c - 22)];
        else if (c < 94)  v = yawr_w[k * 36 + (c - 58)];
        else              v = hgt_w[k * 6 + (c - 94)];
        wh[idx] = v;
    }
    if (idx < 100) {
        int c = idx;
        float v;
        if (c < 4)        v = cate_b[c];
        else if (c < 22)  v = bbox3d_b[c - 4];
        else if (c < 58)  v = yawc_b[c - 22];
        else if (c < 94)  v = yawr_b[c - 58];
        else              v = hgt_b[c - 94];
        bh[c] = v;
    }
}

// ---------------------------------------------------------------------------
// ROI align v2 on (B,HW,C) bf16 feats.  x row layout: k' = bin*256 + c.
// ---------------------------------------------------------------------------
__global__ __launch_bounds__(256) void roi_align_v2_kernel(
    const u16* __restrict__ tf0, const u16* __restrict__ tf1,
    const u16* __restrict__ tf2, const float* __restrict__ bbox2d,
    const int* __restrict__ anchor_id, u16* __restrict__ xb) {
    int bn = blockIdx.x;
    int b = bn >> 9;
    int tid = threadIdx.x;

    __shared__ int s_o00[NSAMP], s_o01[NSAMP], s_o10[NSAMP], s_o11[NSAMP];
    __shared__ float s_w00[NSAMP], s_w01[NSAMP], s_w10[NSAMP], s_w11[NSAMP];

    float cy = bbox2d[bn * 4 + 0], cx = bbox2d[bn * 4 + 1];
    float hh = bbox2d[bn * 4 + 2], ww = bbox2d[bn * 4 + 3];
    int lvl = anchor_id[bn] / 3;
    float scale = (lvl == 0) ? 0.25f : ((lvl == 1) ? 0.125f : 0.0625f);
    int H = (lvl == 0) ? 128 : ((lvl == 1) ? 64 : 32);
    int W = H;

    float t = cy - hh * 0.5f, l = cx - ww * 0.5f;
    float btm = cy + hh * 0.5f, r = cx + ww * 0.5f;
    float sy = t * scale - 0.5f, sx = l * scale - 0.5f;
    float bh = (btm - t) * scale * (1.0f / RESOLUTION);
    float bw = (r - l) * scale * (1.0f / RESOLUTION);

    if (tid < NSAMP) {
        int i = tid / SS, j = tid % SS;
        float gi = (i + 0.5f) * (1.0f / SR);
        float gj = (j + 0.5f) * (1.0f / SR);
        float y = sy + gi * bh, x = sx + gj * bw;
        float valid = (y > -1.0f && y < (float)H && x > -1.0f && x < (float)W)
                          ? 0.25f : 0.0f;
        y = fminf(fmaxf(y, 0.0f), (float)(H - 1));
        x = fminf(fmaxf(x, 0.0f), (float)(W - 1));
        int y0 = (int)floorf(y), x0 = (int)floorf(x);
        int y1 = min(y0 + 1, H - 1), x1 = min(x0 + 1, W - 1);
        float ly = y - (float)y0, lx = x - (float)x0;
        float hy = 1.f - ly, hx = 1.f - lx;
        s_o00[tid] = (y0 * W + x0) * 256;
        s_o01[tid] = (y0 * W + x1) * 256;
        s_o10[tid] = (y1 * W + x0) * 256;
        s_o11[tid] = (y1 * W + x1) * 256;
        s_w00[tid] = hy * hx * valid;
        s_w01[tid] = hy * lx * valid;
        s_w10[tid] = ly * hx * valid;
        s_w11[tid] = ly * lx * valid;
    }
    __syncthreads();

    const u16* fb = (lvl == 0) ? (tf0 + (size_t)b * 16384 * 256)
                  : (lvl == 1) ? (tf1 + (size_t)b * 4096 * 256)
                               : (tf2 + (size_t)b * 1024 * 256);
    int g = tid >> 5;
    int c0 = (tid & 31) * 8;
    u16* xr = xb + (size_t)bn * 12544;

    for (int ii = 0; ii < 7; ++ii) {
        int bin = g + ii * 8;
        if (bin >= 49) break;
        int ph = bin / 7, pw = bin % 7;
        float a[8] = {0.f, 0.f, 0.f, 0.f, 0.f, 0.f, 0.f, 0.f};
        #pragma unroll
        for (int dy = 0; dy < SR; ++dy) {
            #pragma unroll
            for (int dx = 0; dx < SR; ++dx) {
                int si = (ph * SR + dy) * SS + (pw * SR + dx);
                int o00 = s_o00[si], o01 = s_o01[si];
                int o10 = s_o10[si], o11 = s_o11[si];
                float w00 = s_w00[si], w01 = s_w01[si];
                float w10 = s_w10[si], w11 = s_w11[si];
                union { uint4 v; u16 h[8]; } u0, u1, u2, u3;
                u0.v = *(const uint4*)(fb + o00 + c0);
                u1.v = *(const uint4*)(fb + o01 + c0);
                u2.v = *(const uint4*)(fb + o10 + c0);
                u3.v = *(const uint4*)(fb + o11 + c0);
                #pragma unroll
                for (int j = 0; j < 8; ++j) {
                    a[j] = fmaf(bf2f(u0.h[j]), w00, a[j]);
                    a[j] = fmaf(bf2f(u1.h[j]), w01, a[j]);
                    a[j] = fmaf(bf2f(u2.h[j]), w10, a[j]);
                    a[j] = fmaf(bf2f(u3.h[j]), w11, a[j]);
                }
            }
        }
        union { uint4 v; u16 h[8]; } o;
        #pragma unroll
        for (int j = 0; j < 8; ++j) o.h[j] = f2bf(a[j]);
        *(uint4*)&xr[bin * 256 + c0] = o.v;
    }
}

// ---------------------------------------------------------------------------
// zero fill (float4)
// ---------------------------------------------------------------------------
__global__ void zero_kernel(float4* __restrict__ p, int n4) {
    int idx = blockIdx.x * blockDim.x + threadIdx.x;
    if (idx < n4) p[idx] = make_float4(0.f, 0.f, 0.f, 0.f);
}

// ---------------------------------------------------------------------------
// m97-style 128x128 MFMA GEMM with split-K + atomic accumulation.
// Y(M,N) += A(M,K-chunk) @ BT(N,K-chunk)^T    (Y pre-zeroed; fc biases
// cancel in BN)
// ---------------------------------------------------------------------------
__global__ __launch_bounds__(256) void gemm_splitk_kernel(
    const u16* __restrict__ A, const u16* __restrict__ BT,
    float* __restrict__ Y, int M, int N, int K, int KC) {
    __shared__ u16 la[128 * 32];
    __shared__ u16 lb[128 * 32];
    int m0 = blockIdx.x * 128;
    int n0 = blockIdx.y * 128;
    int kbeg = blockIdx.z * KC;
    int tid = threadIdx.x;
    int w = tid >> 6, lane = tid & 63;
    int wm = (w >> 1) * 64, wn = (w & 1) * 64;

    int idx1 = tid + 256;
    const u16* gA0 = A + (size_t)(m0 + (tid >> 2)) * K + (tid & 3) * 8 + kbeg;
    const u16* gA1 = A + (size_t)(m0 + (idx1 >> 2)) * K + (idx1 & 3) * 8 + kbeg;
    const u16* gB0 = BT + (size_t)(n0 + (tid >> 2)) * K + (tid & 3) * 8 + kbeg;
    const u16* gB1 = BT + (size_t)(n0 + (idx1 >> 2)) * K + (idx1 & 3) * 8 + kbeg;
    u16* lA0 = la + w * 512;
    u16* lA1 = la + 2048 + w * 512;
    u16* lB0 = lb + w * 512;
    u16* lB1 = lb + 2048 + w * 512;

    f32x4 acc[4][4] = {};
    int row16 = lane & 15, q8 = (lane >> 4) * 8;

    for (int k0 = 0; k0 < KC; k0 += 32) {
        load_lds16(gA0 + k0, lA0);
        load_lds16(gA1 + k0, lA1);
        load_lds16(gB0 + k0, lB0);
        load_lds16(gB1 + k0, lB1);
        __syncthreads();

        bf16x8 af[4], bf[4];
        #pragma unroll
        for (int tm = 0; tm < 4; ++tm)
            af[tm] = *(const bf16x8*)&la[(wm + tm * 16 + row16) * 32 + q8];
        #pragma unroll
        for (int tn = 0; tn < 4; ++tn)
            bf[tn] = *(const bf16x8*)&lb[(wn + tn * 16 + row16) * 32 + q8];
        #pragma unroll
        for (int tm = 0; tm < 4; ++tm)
            #pragma unroll
            for (int tn = 0; tn < 4; ++tn)
                acc[tm][tn] = __builtin_amdgcn_mfma_f32_16x16x32_bf16(
                    af[tm], bf[tn], acc[tm][tn], 0, 0, 0);
        __syncthreads();
    }

    int col = lane & 15, qr = lane >> 4;
    #pragma unroll
    for (int tm = 0; tm < 4; ++tm) {
        #pragma unroll
        for (int tn = 0; tn < 4; ++tn) {
            int nn = n0 + wn + tn * 16 + col;
            #pragma unroll
            for (int rg = 0; rg < 4; ++rg) {
                int mm = m0 + wm + tm * 16 + qr * 4 + rg;
                unsafeAtomicAdd(&Y[(size_t)mm * N + nn], acc[tm][tn][rg]);
            }
        }
    }
}

// ---------------------------------------------------------------------------
// BN stats stage 1: partial sum/sumsq per 32-row chunk.
// grid (N/256, M/32), block 256 = 64 col-quads x 4 row groups.
// part layout: part[chunk][0][col] sums, part[chunk][1][col] sumsq (2048 f32/chunk)
// ---------------------------------------------------------------------------
__global__ __launch_bounds__(256) void bn_stats_part_kernel(
    const float* __restrict__ y, float* __restrict__ part, int N) {
    int c4 = blockIdx.x * 256 + (threadIdx.x & 63) * 4;
    int rg = threadIdx.x >> 6;
    int r0 = blockIdx.y * 32;
    float4 s = make_float4(0.f, 0.f, 0.f, 0.f);
    float4 q = make_float4(0.f, 0.f, 0.f, 0.f);
    for (int i = 0; i < 8; ++i) {
        int r = r0 + rg + i * 4;
        float4 v = *(const float4*)&y[(size_t)r * N + c4];
        s.x += v.x; s.y += v.y; s.z += v.z; s.w += v.w;
        q.x += v.x * v.x; q.y += v.y * v.y; q.z += v.z * v.z; q.w += v.w * v.w;
    }
    __shared__ float4 ls[4][64], lq[4][64];
    ls[rg][threadIdx.x & 63] = s;
    lq[rg][threadIdx.x & 63] = q;
    __syncthreads();
    if (rg == 0) {
        int cx = threadIdx.x & 63;
        #pragma unroll
        for (int g = 1; g < 4; ++g) {
            float4 a = ls[g][cx], b = lq[g][cx];
            s.x += a.x; s.y += a.y; s.z += a.z; s.w += a.w;
            q.x += b.x; q.y += b.y; q.z += b.z; q.w += b.w;
        }
        float* po = part + (size_t)blockIdx.y * 2048;
        *(float4*)&po[c4] = s;
        *(float4*)&po[1024 + c4] = q;
    }
}

// ---------------------------------------------------------------------------
// BN stats stage 2: reduce 64 chunks -> mean, rstd.  grid 4 x 256 threads.
// ---------------------------------------------------------------------------
__global__ __launch_bounds__(256) void bn_stats_final_kernel(
    const float* __restrict__ part, float* __restrict__ stats, int M, int nchunk) {
    int col = blockIdx.x * 256 + threadIdx.x;
    float s = 0.f, q = 0.f;
    for (int ch = 0; ch < nchunk; ++ch) {
        s += part[(size_t)ch * 2048 + col];
        q += part[(size_t)ch * 2048 + 1024 + col];
    }
    float mean = s / (float)M;
    float var = q / (float)M - mean * mean;
    stats[col] = mean;
    stats[1024 + col] = rsqrtf(var + 1e-5f);
}

// ---------------------------------------------------------------------------
// BN apply + relu -> bf16.  N hardcoded 1024.
// ---------------------------------------------------------------------------
__global__ void bn_apply_kernel(const float* __restrict__ y,
                                const float* __restrict__ stats,
                                const float* __restrict__ g,
                                const float* __restrict__ b,
                                __hip_bfloat16* __restrict__ xo, int total) {
    int idx = blockIdx.x * blockDim.x + threadIdx.x;
    if (idx >= total) return;
    int col = idx & 1023;
    float v = (y[idx] - stats[col]) * stats[1024 + col] * g[col] + b[col];
    xo[idx] = __float2bfloat16(fmaxf(v, 0.f));
}

// ---------------------------------------------------------------------------
// heads: out(2048,100) = x(2048,1024)bf16 @ wh(1024,100)f32 + bh
// ---------------------------------------------------------------------------
__global__ __launch_bounds__(128) void heads_kernel(
    const __hip_bfloat16* __restrict__ x, const float* __restrict__ wh,
    const float* __restrict__ bh, float* __restrict__ out) {
    int m = blockIdx.x;
    __shared__ float lx[1024];
    for (int k = threadIdx.x; k < 1024; k += 128)
        lx[k] = __bfloat162float(x[(size_t)m * 1024 + k]);
    __syncthreads();
    int n = threadIdx.x;
    if (n < 100) {
        float acc = bh[n];
        for (int k = 0; k < 1024; ++k)
            acc += lx[k] * wh[k * 100 + n];
        out[(size_t)m * 100 + n] = acc;
    }
}

// ---------------------------------------------------------------------------
extern "C" void kernel_launch(void* const* d_in, const int* in_sizes, int n_in,
                              void* d_out, int out_size, void* d_ws, size_t ws_size,
                              hipStream_t stream) {
    const float* feat0   = (const float*)d_in[0];
    const float* feat1   = (const float*)d_in[1];
    const float* feat2   = (const float*)d_in[2];
    const float* bbox2d  = (const float*)d_in[3];
    const int*   anchor  = (const int*)d_in[4];
    const float* fc1_w   = (const float*)d_in[5];
    const float* bn1_g   = (const float*)d_in[7];
    const float* bn1_b   = (const float*)d_in[8];
    const float* fc2_w   = (const float*)d_in[9];
    const float* bn2_g   = (const float*)d_in[11];
    const float* bn2_b   = (const float*)d_in[12];
    const float* cate_w  = (const float*)d_in[13];
    const float* cate_b  = (const float*)d_in[14];
    const float* bbox3d_w= (const float*)d_in[15];
    const float* bbox3d_b= (const float*)d_in[16];
    const float* yawc_w  = (const float*)d_in[17];
    const float* yawc_b  = (const float*)d_in[18];
    const float* yawr_w  = (const float*)d_in[19];
    const float* yawr_b  = (const float*)d_in[20];
    const float* hgt_w   = (const float*)d_in[21];
    const float* hgt_b   = (const float*)d_in[22];

    const int B = 4, N = 512, FC = 1024;
    const int M = B * N;   // 2048
    const int K1 = 12544;  // 256*49

    // workspace layout (tf* aliased with post-ROI buffers; disjoint lifetimes)
    char* base = (char*)d_ws;
    u16* xb = (u16*)base;                              // 51,380,224 B
    char* ub = base + 51380224;                        // union, 44,040,192 B
    u16* tf0 = (u16*)ub;                               // 33,554,432
    u16* tf1 = (u16*)(ub + 33554432);                  //  8,388,608
    u16* tf2 = (u16*)(ub + 41943040);                  //  2,097,152
    u16* w1t = (u16*)ub;                               // 25,690,112
    u16* w2t = (u16*)(ub + 25690112);                  //  2,097,152
    float* y   = (float*)(ub + 27787264);              //  8,388,608
    u16* x1b = (u16*)(ub + 36175872);                  //  4,194,304 (end 40,370,176)
    float* part = (float*)(ub + 40370176);             //    524,288 (dead tf2 slice)
    char* tail = ub + 44040192;
    float* stats = (float*)tail;                       // 8 KB
    float* wh    = (float*)(tail + 8192);              // 409,600
    float* bhd   = (float*)(tail + 8192 + 409600);     // 512
    float* outp  = (float*)d_out;

    // 1. head weight concat (independent)
    head_concat_kernel<<<(1024 * 100 + 255) / 256, 256, 0, stream>>>(
        cate_w, bbox3d_w, yawc_w, yawr_w, hgt_w,
        cate_b, bbox3d_b, yawc_b, yawr_b, hgt_b, wh, bhd);

    // 2. feature layout transform (B,C,H,W)f32 -> (B,HW,C)bf16
    transpose_feat_kernel<<<dim3(16384 / 64, B), 256, 0, stream>>>(feat0, tf0, 16384);
    transpose_feat_kernel<<<dim3(4096 / 64, B),  256, 0, stream>>>(feat1, tf1, 4096);
    transpose_feat_kernel<<<dim3(1024 / 64, B),  256, 0, stream>>>(feat2, tf2, 1024);

    // 3. ROI align -> x bf16 (M, K1), k' = bin*256 + c layout
    roi_align_v2_kernel<<<M, 256, 0, stream>>>(tf0, tf1, tf2, bbox2d, anchor, xb);

    // 4. weight transposes (overwrite tf* region — after roi)
    transpose_w_kernel<<<dim3(K1 / 64, FC / 64), 256, 0, stream>>>(fc1_w, w1t, K1, 1);
    transpose_w_kernel<<<dim3(FC / 64, FC / 64), 256, 0, stream>>>(fc2_w, w2t, FC, 0);

    // 5. fc1 (split-K=4, atomic accumulate into zeroed y) + BN1
    zero_kernel<<<(M * FC / 4 + 255) / 256, 256, 0, stream>>>((float4*)y, M * FC / 4);
    gemm_splitk_kernel<<<dim3(M / 128, FC / 128, 4), 256, 0, stream>>>(
        xb, w1t, y, M, FC, K1, K1 / 4);
    bn_stats_part_kernel<<<dim3(FC / 256, M / 32), 256, 0, stream>>>(y, part, FC);
    bn_stats_final_kernel<<<FC / 256, 256, 0, stream>>>(part, stats, M, M / 32);
    bn_apply_kernel<<<(M * FC + 255) / 256, 256, 0, stream>>>(
        y, stats, bn1_g, bn1_b, (__hip_bfloat16*)x1b, M * FC);

    // 6. fc2 (split-K=4) + BN2
    zero_kernel<<<(M * FC / 4 + 255) / 256, 256, 0, stream>>>((float4*)y, M * FC / 4);
    gemm_splitk_kernel<<<dim3(M / 128, FC / 128, 4), 256, 0, stream>>>(
        x1b, w2t, y, M, FC, FC, FC / 4);
    bn_stats_part_kernel<<<dim3(FC / 256, M / 32), 256, 0, stream>>>(y, part, FC);
    bn_stats_final_kernel<<<FC / 256, 256, 0, stream>>>(part, stats, M, M / 32);
    bn_apply_kernel<<<(M * FC + 255) / 256, 256, 0, stream>>>(
        y, stats, bn2_g, bn2_b, (__hip_bfloat16*)x1b, M * FC);

    // 7. heads -> d_out
    heads_kernel<<<M, 128, 0, stream>>>((const __hip_bfloat16*)x1b, wh, bhd, outp);
}